// Round 1
// 1468.597 us; speedup vs baseline: 1.0636x; 1.0636x over previous
//
#include <hip/hip_runtime.h>

typedef __attribute__((ext_vector_type(8))) short short8;
typedef __attribute__((ext_vector_type(4))) float floatx4;

__device__ __forceinline__ float b2f(ushort us) {
    union { unsigned u; float f; } v; v.u = ((unsigned)us) << 16; return v.f;
}
__device__ __forceinline__ ushort f2b(float f) {
    union { float f; unsigned u; } v; v.f = f;
    unsigned r = (v.u + 0x7fffu + ((v.u >> 16) & 1u)) >> 16;
    return (ushort)r;
}
__device__ __forceinline__ float ldany(const void* p, long i, int bf) {
    return bf ? b2f(((const ushort*)p)[i]) : ((const float*)p)[i];
}
__device__ __forceinline__ void async16(const ushort* g, ushort* l) {
    __builtin_amdgcn_global_load_lds((const __attribute__((address_space(1))) void*)g,
                                     (__attribute__((address_space(3))) void*)l,
                                     16, 0, 0);
}

// ---------------------------------------------------------------------------
// dtype detector: low-ushort exponent field of fp32 words is uniform random;
// of bf16 elements of N(0,~0.02) weights it concentrates in [112,128].
// ---------------------------------------------------------------------------
__global__ void detect_dtype(const unsigned* __restrict__ w, int* __restrict__ flag)
{
    if (threadIdx.x == 0 && blockIdx.x == 0) {
        int votes = 0;
        for (int i = 0; i < 256; i++) {
            unsigned e = (w[i] >> 7) & 0xFFu;   // bf16 exponent of low half
            if (e >= 112u && e <= 128u) votes++;
        }
        *flag = (votes >= 128) ? 1 : 0;          // 1 = buffers are bf16
    }
}

// ---------------------------------------------------------------------------
// Transpose [R][C] (fp32 or bf16) -> bf16 [C][R]
// ---------------------------------------------------------------------------
__global__ __launch_bounds__(256) void transpose_any(
    const void* __restrict__ in, long in_off, ushort* __restrict__ out,
    int R, int C, const int* __restrict__ flag)
{
    __shared__ float tile[64][65];
    const int bf = *flag;
    const int t  = threadIdx.x;
    const long r0 = (long)blockIdx.y * 64;
    const long c0 = (long)blockIdx.x * 64;
    const int rl = t >> 4;
    const int cl = (t & 15) * 4;
    #pragma unroll
    for (int p = 0; p < 4; p++) {
        const int r = rl + p * 16;
        const long base = in_off + (r0 + r) * C + c0 + cl;
        if (bf) {
            ushort4 v = *(const ushort4*)((const ushort*)in + base);
            tile[r][cl + 0] = b2f(v.x); tile[r][cl + 1] = b2f(v.y);
            tile[r][cl + 2] = b2f(v.z); tile[r][cl + 3] = b2f(v.w);
        } else {
            float4 v = *(const float4*)((const float*)in + base);
            tile[r][cl + 0] = v.x; tile[r][cl + 1] = v.y;
            tile[r][cl + 2] = v.z; tile[r][cl + 3] = v.w;
        }
    }
    __syncthreads();
    #pragma unroll
    for (int p = 0; p < 4; p++) {
        const int oc = rl + p * 16;          // output row = original column
        ushort4 v;
        v.x = f2b(tile[cl + 0][oc]); v.y = f2b(tile[cl + 1][oc]);
        v.z = f2b(tile[cl + 2][oc]); v.w = f2b(tile[cl + 3][oc]);
        *(ushort4*)(out + (c0 + oc) * R + r0 + cl) = v;
    }
}

// ---------------------------------------------------------------------------
// raw (fp32 or bf16) -> bf16, 4 elements/thread
// ---------------------------------------------------------------------------
__global__ void to_bf16_any(const void* __restrict__ in, ushort* __restrict__ out,
                            long n4, const int* __restrict__ flag)
{
    const long i = (long)blockIdx.x * blockDim.x + threadIdx.x;
    if (i >= n4) return;
    const int bf = *flag;
    ushort4 o;
    if (bf) {
        o = ((const ushort4*)in)[i];
    } else {
        float4 v = ((const float4*)in)[i];
        o.x = f2b(v.x); o.y = f2b(v.y); o.z = f2b(v.z); o.w = f2b(v.w);
    }
    ((ushort4*)out)[i] = o;
}

// fp32 -> bf16 (internal, no flag), 4/thread
__global__ void f32_to_bf16_4(const float* __restrict__ in, ushort* __restrict__ out, long n4)
{
    const long i = (long)blockIdx.x * blockDim.x + threadIdx.x;
    if (i >= n4) return;
    float4 v = ((const float4*)in)[i];
    ushort4 o; o.x = f2b(v.x); o.y = f2b(v.y); o.z = f2b(v.z); o.w = f2b(v.w);
    ((ushort4*)out)[i] = o;
}

// ---------------------------------------------------------------------------
// 8-phase counted-vmcnt bf16 GEMM (T2 swizzle + T3/T4 pipeline + T5 setprio).
// C[M,N] = A[M,K] * Bt[N,K]^T, fused epilogues.
//   MF=8: BM=256 (grid.y=M/256), MF=4: BM=128 (grid.y=M/128). BN=256 fixed.
//   512 threads = 8 waves (2M x 4N). BK=64, double-buffered LDS.
// LDS swizzle: 16B-chunk index c' = c ^ (row&7), applied on the ds_read
// address AND pre-applied on the per-lane GLOBAL source of global_load_lds
// (LDS dest stays linear: wave-uniform base + lane*16).
// ---------------------------------------------------------------------------
#define EPI_SILU   0   // out_bf16 = silu(acc + bias)
#define EPI_BIAS   1   // out_bf16 = acc + bias
#define EPI_EXPERT 2   // hacc += rowscale[m*4] * (acc + bias)
#define EPI_CTX    3   // hacc += acc + bias
#define EPI_OUT    4   // out(any) = acc + bias + resid_bf16[m*N+n]

#define BAR()        __builtin_amdgcn_s_barrier()
#define WAIT_LGKM0() asm volatile("s_waitcnt lgkmcnt(0)" ::: "memory")
#define WAIT_VM6()   asm volatile("s_waitcnt vmcnt(6)" ::: "memory")
#define WAIT_VM5()   asm volatile("s_waitcnt vmcnt(5)" ::: "memory")
#define WAIT_VM0()   asm volatile("s_waitcnt vmcnt(0)" ::: "memory")

// stage one A half-tile (H=0/1) of K-tile KT into buffer BUF
#define STAGE_A(BUF, H, KT) do {                                               \
    const long _k0 = (long)(KT) << 6;                                          \
    _Pragma("unroll")                                                          \
    for (int _i = 0; _i < AINSTR; ++_i) {                                      \
        const int _gi   = w + _i * 8;                                          \
        const int _s    = _gi / AHALF_GRP;                                     \
        const int _wg   = _gi % AHALF_GRP;                                     \
        const int _row0 = _s * (BM / 2) + (H) * (BM / 4) + _wg * 8;            \
        const int _grow = _row0 + (lane >> 3);                                 \
        async16(A + (m0 + _grow) * (long)K + _k0 +                             \
                    (((lane & 7) ^ (_grow & 7)) << 3),                         \
                smem + (BUF) * BUFU + _row0 * 64);                             \
    } } while (0)

// stage one B half-tile (H=0/1) of K-tile KT into buffer BUF
#define STAGE_B(BUF, H, KT) do {                                               \
    const long _k0 = (long)(KT) << 6;                                          \
    _Pragma("unroll")                                                          \
    for (int _i = 0; _i < 2; ++_i) {                                           \
        const int _gi   = w * 2 + _i;                                          \
        const int _row0 = (_gi >> 2) * 64 + (H) * 32 + (_gi & 3) * 8;          \
        const int _grow = _row0 + (lane >> 3);                                 \
        async16(Bt + (n0 + _grow) * (long)K + _k0 +                            \
                     (((lane & 7) ^ (_grow & 7)) << 3),                        \
                smem + (BUF) * BUFU + BM * 64 + _row0 * 64);                   \
    } } while (0)

// read A fragments for m-half MH into a[][] (swizzled ds_read_b128)
#define LOAD_A(BUF, MH) do {                                                   \
    _Pragma("unroll")                                                          \
    for (int _m = 0; _m < MF / 2; ++_m) {                                      \
        const int _row = wm * (BM / 2) + ((MH) * (MF / 2) + _m) * 16 + fr;     \
        _Pragma("unroll")                                                      \
        for (int _ks = 0; _ks < 2; ++_ks)                                      \
            a[_m][_ks] = *(const short8*)(smem + (BUF) * BUFU + _row * 64 +    \
                                          (((_ks * 4 + q) ^ (_row & 7)) << 3));\
    } } while (0)

// read B fragments for n-half NH into BREG[][]
#define LOAD_B(BUF, NH, BREG) do {                                             \
    _Pragma("unroll")                                                          \
    for (int _n = 0; _n < 2; ++_n) {                                           \
        const int _row = wn * 64 + ((NH) * 2 + _n) * 16 + fr;                  \
        _Pragma("unroll")                                                      \
        for (int _ks = 0; _ks < 2; ++_ks)                                      \
            BREG[_n][_ks] = *(const short8*)(smem + (BUF) * BUFU + BM * 64 +   \
                                             _row * 64 +                       \
                                          (((_ks * 4 + q) ^ (_row & 7)) << 3));\
    } } while (0)

// 16 (MF=8) / 8 (MF=4) MFMAs: quadrant (MH,NH) x K=64
#define MMA(MH, NH, BREG) do {                                                 \
    _Pragma("unroll")                                                          \
    for (int _m = 0; _m < MF / 2; ++_m)                                        \
    _Pragma("unroll")                                                          \
    for (int _n = 0; _n < 2; ++_n)                                             \
    _Pragma("unroll")                                                          \
    for (int _ks = 0; _ks < 2; ++_ks)                                          \
        acc[(MH) * (MF / 2) + _m][(NH) * 2 + _n] =                             \
            __builtin_amdgcn_mfma_f32_16x16x32_bf16(                           \
                a[_m][_ks], BREG[_n][_ks],                                     \
                acc[(MH) * (MF / 2) + _m][(NH) * 2 + _n], 0, 0, 0);            \
    } while (0)

template<int EPI, int MF>
__global__ __launch_bounds__(512, 2) void gemm8(
    const ushort* __restrict__ A, const ushort* __restrict__ Bt,
    int M, int N, int K,
    const void* __restrict__ bias, long bias_off,
    void* __restrict__ out, long ldo,
    float* __restrict__ hacc,
    const float* __restrict__ rowscale,
    const ushort* __restrict__ resid,
    const int* __restrict__ flag)
{
    constexpr int BM        = MF * 32;        // 128 or 256
    constexpr int AHALF_GRP = BM / 32;        // 8-row groups per section per A-half
    constexpr int AINSTR    = BM / 128;       // global_load_lds per wave per A-half
    constexpr int BUFU      = (BM + 256) * 64;// ushorts per double-buffer slot
    extern __shared__ ushort smem[];

    const int tid  = threadIdx.x;
    const int lane = tid & 63;
    const int w    = tid >> 6;
    const int wm   = w >> 2;                  // 0..1
    const int wn   = w & 3;                   // 0..3
    const int fr   = lane & 15;
    const int q    = lane >> 4;
    const long m0  = (long)blockIdx.y * BM;
    const long n0  = (long)blockIdx.x * 256;
    const int NT   = K >> 6;                  // K-tiles of 64 (K>=2048 here)

    floatx4 acc[MF][4] = {};
    short8 a[MF / 2][2];
    short8 b0[2][2], b1[2][2];

    // prologue: tile0 fully + 3 half-tiles of tile1 (order matches steady state)
    STAGE_A(0, 0, 0); STAGE_A(0, 1, 0); STAGE_B(0, 0, 0); STAGE_B(0, 1, 0);
    STAGE_A(1, 0, 1); STAGE_B(1, 0, 1); STAGE_B(1, 1, 1);
    if constexpr (MF == 8) WAIT_VM6(); else WAIT_VM5();   // tile0 resident
    BAR();

    for (int t = 0; t < NT; ++t) {
        const int cur = t & 1, nxt = cur ^ 1;
        // ---- P1: quadrant (0,0); stage A-half1 of tile t+1 -----------------
        LOAD_A(cur, 0);
        LOAD_B(cur, 0, b0);
        if (t + 1 < NT) STAGE_A(nxt, 1, t + 1);
        BAR(); WAIT_LGKM0();
        __builtin_amdgcn_s_setprio(1); MMA(0, 0, b0); __builtin_amdgcn_s_setprio(0);
        BAR();
        // ---- P2: quadrant (0,1); stage A-half0 of tile t+2 -----------------
        LOAD_B(cur, 1, b1);
        if (t + 2 < NT) STAGE_A(cur, 0, t + 2);
        BAR(); WAIT_LGKM0();
        __builtin_amdgcn_s_setprio(1); MMA(0, 1, b1); __builtin_amdgcn_s_setprio(0);
        BAR();
        // ---- P3: quadrant (1,1); stage B-half0 of tile t+2 -----------------
        LOAD_A(cur, 1);
        if (t + 2 < NT) STAGE_B(cur, 0, t + 2);
        BAR(); WAIT_LGKM0();
        __builtin_amdgcn_s_setprio(1); MMA(1, 1, b1); __builtin_amdgcn_s_setprio(0);
        BAR();
        // ---- P4: quadrant (1,0); stage B-half1 of tile t+2; counted vmcnt --
        if (t + 2 < NT) {
            STAGE_B(cur, 1, t + 2);
            if constexpr (MF == 8) WAIT_VM6(); else WAIT_VM5();
        } else {
            WAIT_VM0();                       // tail drain (last two tiles only)
        }
        BAR();
        __builtin_amdgcn_s_setprio(1); MMA(1, 0, b0); __builtin_amdgcn_s_setprio(0);
        BAR();
    }

    const int bf = *flag;
    // C[m][n]: m = i*16 + q*4 + r, n = j*16 + fr (m89-verified layout)
    #pragma unroll
    for (int i = 0; i < MF; ++i) {
        #pragma unroll
        for (int r = 0; r < 4; ++r) {
            const long m = m0 + wm * (BM / 2) + i * 16 + q * 4 + r;
            #pragma unroll
            for (int j = 0; j < 4; ++j) {
                const long n = n0 + wn * 64 + j * 16 + fr;
                float v = acc[i][j][r] + ldany(bias, bias_off + n, bf);
                if (EPI == EPI_SILU) {
                    v = v / (1.f + __expf(-v));
                    ((ushort*)out)[m * ldo + n] = f2b(v);
                } else if (EPI == EPI_BIAS) {
                    ((ushort*)out)[m * ldo + n] = f2b(v);
                } else if (EPI == EPI_EXPERT) {
                    hacc[m * (long)N + n] += rowscale[m * 4] * v;
                } else if (EPI == EPI_CTX) {
                    hacc[m * (long)N + n] += v;
                } else {
                    v += b2f(resid[m * (long)N + n]);
                    if (bf) ((ushort*)out)[m * ldo + n] = f2b(v);
                    else    ((float*)out)[m * ldo + n]  = v;
                }
            }
        }
    }
}

// ---------------------------------------------------------------------------
// se gather: hA[m][2048 + j] = bf16(W_syn_emb[ids[m]][j]), j < 512
// ---------------------------------------------------------------------------
__global__ void gather_syn(const int* __restrict__ ids, const void* __restrict__ emb,
                           ushort* __restrict__ hA, const int* __restrict__ flag)
{
    const int bf = *flag;
    const long m = blockIdx.x;
    const int id = ids[m];
    const int j = threadIdx.x * 2;
    float a, b;
    if (bf) {
        ushort2 v = *(const ushort2*)((const ushort*)emb + (long)id * 512 + j);
        a = b2f(v.x); b = b2f(v.y);
    } else {
        float2 v = *(const float2*)((const float*)emb + (long)id * 512 + j);
        a = v.x; b = v.y;
    }
    ushort2 o; o.x = f2b(a); o.y = f2b(b);
    *(ushort2*)(hA + m * 2560 + 2048 + j) = o;
}

// ---------------------------------------------------------------------------
// gate + router; h3 = h2*gate in place (bf16) and into hacc (fp32)
// ---------------------------------------------------------------------------
__global__ __launch_bounds__(256) void gate_router(
    ushort* __restrict__ h2, float* __restrict__ hacc, float* __restrict__ probs,
    const void* __restrict__ Wg, const void* __restrict__ bg,
    const void* __restrict__ Wr, const void* __restrict__ br,
    const int* __restrict__ flag)
{
    const int bf = *flag;
    const long m = blockIdx.x;
    const int t = threadIdx.x;
    const int lane = t & 63;
    const int wv = t >> 6;
    ushort* row = h2 + m * 2048;

    float sg = 0.f, s0 = 0.f, s1 = 0.f, s2 = 0.f, s3 = 0.f;
    for (int k = t; k < 2048; k += 256) {
        const float h = b2f(row[k]);
        sg += h * ldany(Wg, k, bf);
        float r0v, r1v, r2v, r3v;
        if (bf) {
            ushort4 v = *(const ushort4*)((const ushort*)Wr + (long)k * 4);
            r0v = b2f(v.x); r1v = b2f(v.y); r2v = b2f(v.z); r3v = b2f(v.w);
        } else {
            float4 v = *(const float4*)((const float*)Wr + (long)k * 4);
            r0v = v.x; r1v = v.y; r2v = v.z; r3v = v.w;
        }
        s0 += h * r0v; s1 += h * r1v; s2 += h * r2v; s3 += h * r3v;
    }
    #pragma unroll
    for (int off = 32; off > 0; off >>= 1) {
        sg += __shfl_down(sg, off);
        s0 += __shfl_down(s0, off);
        s1 += __shfl_down(s1, off);
        s2 += __shfl_down(s2, off);
        s3 += __shfl_down(s3, off);
    }
    __shared__ float red[4][5];
    __shared__ float gate_bc;
    if (lane == 0) {
        red[wv][0] = sg; red[wv][1] = s0; red[wv][2] = s1;
        red[wv][3] = s2; red[wv][4] = s3;
    }
    __syncthreads();
    if (t == 0) {
        float G = red[0][0] + red[1][0] + red[2][0] + red[3][0];
        float R[4];
        #pragma unroll
        for (int e = 0; e < 4; e++)
            R[e] = red[0][1 + e] + red[1][1 + e] + red[2][1 + e] + red[3][1 + e];
        const float gate = 1.f / (1.f + __expf(-(G + ldany(bg, 0, bf))));
        float lg[4], mx = -1e30f;
        #pragma unroll
        for (int e = 0; e < 4; e++) {
            lg[e] = gate * R[e] + ldany(br, e, bf);
            mx = fmaxf(mx, lg[e]);
        }
        float p[4], s = 0.f;
        #pragma unroll
        for (int e = 0; e < 4; e++) { p[e] = __expf(lg[e] - mx); s += p[e]; }
        #pragma unroll
        for (int e = 0; e < 4; e++) probs[m * 4 + e] = p[e] / s;
        gate_bc = gate;
    }
    __syncthreads();
    const float gate = gate_bc;
    for (int k = t; k < 2048; k += 256) {
        const float v = b2f(row[k]) * gate;
        row[k] = f2b(v);
        hacc[m * 2048 + k] = v;
    }
}

// ---------------------------------------------------------------------------
// grouped conv1d (8 ch/group, k=3, pad 1) + combine: h5 = bf16(hacc + cb + pat)
// ---------------------------------------------------------------------------
__global__ __launch_bounds__(256) void conv_combine(
    const ushort* __restrict__ h4, const float* __restrict__ hacc,
    const void* __restrict__ cw, const void* __restrict__ cb,
    ushort* __restrict__ h5, const int* __restrict__ flag)
{
    const int S = 2048, D = 2048;
    const int bf = *flag;
    const int b = blockIdx.z, g = blockIdx.y;
    const int s0 = blockIdx.x * 64;
    __shared__ float tile[66 * 8];
    const int t = threadIdx.x;
    for (int idx = t; idx < 66 * 8; idx += 256) {
        const int sl = idx >> 3, i = idx & 7;
        const int s = s0 + sl - 1;
        float v = 0.f;
        if (s >= 0 && s < S) v = b2f(h4[((long)b * S + s) * D + g * 8 + i]);
        tile[idx] = v;
    }
    __syncthreads();
    const int io = t & 7;
    const int c = g * 8 + io;
    float w[3][8];
    #pragma unroll
    for (int kk = 0; kk < 3; kk++)
        #pragma unroll
        for (int ii = 0; ii < 8; ii++)
            w[kk][ii] = ldany(cw, (long)c * 24 + ii * 3 + kk, bf);
    const float bc = ldany(cb, c, bf);
    #pragma unroll
    for (int p = 0; p < 2; p++) {
        const int sl = (t >> 3) + p * 32;
        float pat = 0.f;
        #pragma unroll
        for (int kk = 0; kk < 3; kk++)
            #pragma unroll
            for (int ii = 0; ii < 8; ii++)
                pat += tile[(sl + kk) * 8 + ii] * w[kk][ii];
        const long m = (long)b * S + s0 + sl;
        h5[m * D + c] = f2b(hacc[m * D + c] + bc + pat);
    }
}

// ---------------------------------------------------------------------------
extern "C" void kernel_launch(void* const* d_in, const int* in_sizes, int n_in,
                              void* d_out, int out_size, void* d_ws, size_t ws_size,
                              hipStream_t stream)
{
    (void)in_sizes; (void)n_in; (void)out_size; (void)ws_size;
    const void* x        = d_in[0];
    const int*  syn      = (const int*)d_in[1];
    const void* W_in     = d_in[2];
    const void* b_in     = d_in[3];
    const void* W_synemb = d_in[4];
    const void* W_syn    = d_in[5];
    const void* b_syn    = d_in[6];
    const void* W_gate   = d_in[7];
    const void* b_gate   = d_in[8];
    const void* W_router = d_in[9];
    const void* b_router = d_in[10];
    const void* W_e1     = d_in[11];
    const void* b_e1     = d_in[12];
    const void* W_e2     = d_in[13];
    const void* b_e2     = d_in[14];
    const void* W_ctx    = d_in[15];
    const void* b_ctx    = d_in[16];
    const void* conv_w   = d_in[17];
    const void* conv_b   = d_in[18];
    const void* W_out    = d_in[19];
    const void* b_out    = d_in[20];

    char* ws = (char*)d_ws;
    int*    flag  = (int*)ws;                          // 256 B reserved
    ushort* WT    = (ushort*)(ws + 256);               // 16 MiB transposed weight
    ushort* xb    = (ushort*)(ws + 16777472);          // [4096][2048] bf16 x
    ushort* hA    = (ushort*)(ws + 33554688);          // [4096][2560] concat(h1,se); later h5 (ld 2048)
    ushort* eh    = (ushort*)(ws + 16777472);          // [4096][4096] overlaps xb+hA-head (expert phase only)
    ushort* h23   = (ushort*)(ws + 54526208);          // [4096][2048] h2 -> h3 -> h4(bf16)
    float*  probs = (float*)(ws + 71303424);           // [4096][4]
    float*  hacc  = (float*)(ws + 71368960);           // [4096][2048] fp32 accumulator
    const int M = 4096;
    dim3 blk(256);
    const int LDS4 = 98304;    // MF=4: 2*(128+256)*64*2 B
    const int LDS8 = 131072;   // MF=8: 2*(256+256)*64*2 B

    static bool attr_set = false;
    if (!attr_set) {
        (void)hipFuncSetAttribute(reinterpret_cast<const void*>(&gemm8<EPI_SILU,   4>),
                                  hipFuncAttributeMaxDynamicSharedMemorySize, LDS4);
        (void)hipFuncSetAttribute(reinterpret_cast<const void*>(&gemm8<EPI_BIAS,   4>),
                                  hipFuncAttributeMaxDynamicSharedMemorySize, LDS4);
        (void)hipFuncSetAttribute(reinterpret_cast<const void*>(&gemm8<EPI_EXPERT, 4>),
                                  hipFuncAttributeMaxDynamicSharedMemorySize, LDS4);
        (void)hipFuncSetAttribute(reinterpret_cast<const void*>(&gemm8<EPI_CTX,    4>),
                                  hipFuncAttributeMaxDynamicSharedMemorySize, LDS4);
        (void)hipFuncSetAttribute(reinterpret_cast<const void*>(&gemm8<EPI_OUT,    4>),
                                  hipFuncAttributeMaxDynamicSharedMemorySize, LDS4);
        (void)hipFuncSetAttribute(reinterpret_cast<const void*>(&gemm8<EPI_SILU,   8>),
                                  hipFuncAttributeMaxDynamicSharedMemorySize, LDS8);
        attr_set = true;
    }

    // 0) dtype probe (re-runs every launch; ws is re-poisoned by harness)
    detect_dtype<<<dim3(1), dim3(64), 0, stream>>>((const unsigned*)W_in, flag);
    // 0b) xb = bf16(x)  [also the bf16 residual source for step 9]
    to_bf16_any<<<dim3(8192), blk, 0, stream>>>(x, xb, 2097152L, flag);

    // 1) h1 = silu(x @ W_in + b_in) -> hA[:, :2048] (ld 2560)
    transpose_any<<<dim3(32, 32), blk, 0, stream>>>(W_in, 0, WT, 2048, 2048, flag);
    gemm8<EPI_SILU, 4><<<dim3(8, 32), dim3(512), LDS4, stream>>>(
        xb, WT, M, 2048, 2048, b_in, 0, hA, 2560, nullptr, nullptr, nullptr, flag);
    // 2) se gather -> hA[:, 2048:2560]
    gather_syn<<<dim3(4096), blk, 0, stream>>>(syn, W_synemb, hA, flag);
    // 3) h2 = concat(h1,se) @ W_syn + b_syn -> h23
    transpose_any<<<dim3(32, 40), blk, 0, stream>>>(W_syn, 0, WT, 2560, 2048, flag);
    gemm8<EPI_BIAS, 4><<<dim3(8, 32), dim3(512), LDS4, stream>>>(
        hA, WT, M, 2048, 2560, b_syn, 0, h23, 2048, nullptr, nullptr, nullptr, flag);
    // 4) gate + router; h3 in place; hacc = h3
    gate_router<<<dim3(4096), blk, 0, stream>>>(
        h23, hacc, probs, W_gate, b_gate, W_router, b_router, flag);
    // 5) experts: hacc += probs_e * (silu(h3 @ We1 + b1) @ We2 + b2)
    for (int e = 0; e < 4; e++) {
        transpose_any<<<dim3(64, 32), blk, 0, stream>>>(
            W_e1, (long)e * 8388608, WT, 2048, 4096, flag);
        gemm8<EPI_SILU, 8><<<dim3(16, 16), dim3(512), LDS8, stream>>>(
            h23, WT, M, 4096, 2048, b_e1, (long)e * 4096, eh, 4096,
            nullptr, nullptr, nullptr, flag);
        transpose_any<<<dim3(32, 64), blk, 0, stream>>>(
            W_e2, (long)e * 8388608, WT, 4096, 2048, flag);
        gemm8<EPI_EXPERT, 4><<<dim3(8, 32), dim3(512), LDS4, stream>>>(
            eh, WT, M, 2048, 4096, b_e2, (long)e * 2048, nullptr, 0,
            hacc, probs + e, nullptr, flag);
    }
    // 5b) restore xb (eh clobbered it)
    to_bf16_any<<<dim3(8192), blk, 0, stream>>>(x, xb, 2097152L, flag);
    // 6) h4 snapshot (bf16) into h23
    f32_to_bf16_4<<<dim3(8192), blk, 0, stream>>>(hacc, h23, 2097152L);
    // 7) hacc += h4 @ W_ctx + b_ctx
    transpose_any<<<dim3(32, 32), blk, 0, stream>>>(W_ctx, 0, WT, 2048, 2048, flag);
    gemm8<EPI_CTX, 4><<<dim3(8, 32), dim3(512), LDS4, stream>>>(
        h23, WT, M, 2048, 2048, b_ctx, 0, nullptr, 0, hacc, nullptr, nullptr, flag);
    // 8) h5 = bf16(hacc + conv_b + grouped_conv(h4)) -> hA (ld 2048)
    conv_combine<<<dim3(32, 256, 2), blk, 0, stream>>>(
        h23, hacc, conv_w, conv_b, hA, flag);
    // 9) out = h5 @ W_out + b_out + x
    transpose_any<<<dim3(32, 32), blk, 0, stream>>>(W_out, 0, WT, 2048, 2048, flag);
    gemm8<EPI_OUT, 4><<<dim3(8, 32), dim3(512), LDS4, stream>>>(
        hA, WT, M, 2048, 2048, b_out, 0, d_out, 2048, nullptr, nullptr, xb, flag);
}

// Round 2
// 1395.093 us; speedup vs baseline: 1.1196x; 1.0527x over previous
//
#include <hip/hip_runtime.h>

typedef __attribute__((ext_vector_type(8))) short short8;
typedef __attribute__((ext_vector_type(4))) float floatx4;

__device__ __forceinline__ float b2f(ushort us) {
    union { unsigned u; float f; } v; v.u = ((unsigned)us) << 16; return v.f;
}
__device__ __forceinline__ ushort f2b(float f) {
    union { float f; unsigned u; } v; v.f = f;
    unsigned r = (v.u + 0x7fffu + ((v.u >> 16) & 1u)) >> 16;
    return (ushort)r;
}
__device__ __forceinline__ float ldany(const void* p, long i, int bf) {
    return bf ? b2f(((const ushort*)p)[i]) : ((const float*)p)[i];
}
__device__ __forceinline__ void async16(const ushort* g, ushort* l) {
    __builtin_amdgcn_global_load_lds((const __attribute__((address_space(1))) void*)g,
                                     (__attribute__((address_space(3))) void*)l,
                                     16, 0, 0);
}

// ---------------------------------------------------------------------------
// dtype detector: low-ushort exponent field of fp32 words is uniform random;
// of bf16 elements of N(0,~0.02) weights it concentrates in [112,128].
// ---------------------------------------------------------------------------
__global__ void detect_dtype(const unsigned* __restrict__ w, int* __restrict__ flag)
{
    if (threadIdx.x == 0 && blockIdx.x == 0) {
        int votes = 0;
        for (int i = 0; i < 256; i++) {
            unsigned e = (w[i] >> 7) & 0xFFu;   // bf16 exponent of low half
            if (e >= 112u && e <= 128u) votes++;
        }
        *flag = (votes >= 128) ? 1 : 0;          // 1 = buffers are bf16
    }
}

// ---------------------------------------------------------------------------
// Transpose [R][C] (fp32 or bf16) -> bf16 [C][R]
// ---------------------------------------------------------------------------
__global__ __launch_bounds__(256) void transpose_any(
    const void* __restrict__ in, long in_off, ushort* __restrict__ out,
    int R, int C, const int* __restrict__ flag)
{
    __shared__ float tile[64][65];
    const int bf = *flag;
    const int t  = threadIdx.x;
    const long r0 = (long)blockIdx.y * 64;
    const long c0 = (long)blockIdx.x * 64;
    const int rl = t >> 4;
    const int cl = (t & 15) * 4;
    #pragma unroll
    for (int p = 0; p < 4; p++) {
        const int r = rl + p * 16;
        const long base = in_off + (r0 + r) * C + c0 + cl;
        if (bf) {
            ushort4 v = *(const ushort4*)((const ushort*)in + base);
            tile[r][cl + 0] = b2f(v.x); tile[r][cl + 1] = b2f(v.y);
            tile[r][cl + 2] = b2f(v.z); tile[r][cl + 3] = b2f(v.w);
        } else {
            float4 v = *(const float4*)((const float*)in + base);
            tile[r][cl + 0] = v.x; tile[r][cl + 1] = v.y;
            tile[r][cl + 2] = v.z; tile[r][cl + 3] = v.w;
        }
    }
    __syncthreads();
    #pragma unroll
    for (int p = 0; p < 4; p++) {
        const int oc = rl + p * 16;          // output row = original column
        ushort4 v;
        v.x = f2b(tile[cl + 0][oc]); v.y = f2b(tile[cl + 1][oc]);
        v.z = f2b(tile[cl + 2][oc]); v.w = f2b(tile[cl + 3][oc]);
        *(ushort4*)(out + (c0 + oc) * R + r0 + cl) = v;
    }
}

// ---------------------------------------------------------------------------
// raw (fp32 or bf16) -> bf16, 4 elements/thread
// ---------------------------------------------------------------------------
__global__ void to_bf16_any(const void* __restrict__ in, ushort* __restrict__ out,
                            long n4, const int* __restrict__ flag)
{
    const long i = (long)blockIdx.x * blockDim.x + threadIdx.x;
    if (i >= n4) return;
    const int bf = *flag;
    ushort4 o;
    if (bf) {
        o = ((const ushort4*)in)[i];
    } else {
        float4 v = ((const float4*)in)[i];
        o.x = f2b(v.x); o.y = f2b(v.y); o.z = f2b(v.z); o.w = f2b(v.w);
    }
    ((ushort4*)out)[i] = o;
}

// ---------------------------------------------------------------------------
// 8-phase counted-vmcnt bf16 GEMM (T2 swizzle + T3/T4 pipeline + T5 setprio).
// C[M,N] = A[M,K] * Bt[N,K]^T, fused epilogues.
//   MF=8: BM=256 (grid.y=M/256), MF=4: BM=128 (grid.y=M/128). BN=256 fixed.
//   512 threads = 8 waves (2M x 4N). BK=64, double-buffered LDS.
// LDS swizzle: 16B-chunk index c' = c ^ (row&7), applied on the ds_read
// address AND pre-applied on the per-lane GLOBAL source of global_load_lds
// (LDS dest stays linear: wave-uniform base + lane*16).
// ---------------------------------------------------------------------------
#define EPI_SILU    0   // out_bf16 = silu(acc + bias)
#define EPI_BIAS    1   // out_bf16 = acc + bias
#define EPI_EXPERT  2   // hacc += rowscale[m*4] * (acc + bias)
#define EPI_CTX     3   // hacc += acc + bias
#define EPI_OUT     4   // out(any) = acc + bias + resid_bf16[m*N+n]
#define EPI_EXPSNAP 5   // hacc += rowscale*(acc+bias); out_bf16 = f2b(hacc_new)

#define BAR()        __builtin_amdgcn_s_barrier()
#define WAIT_LGKM0() asm volatile("s_waitcnt lgkmcnt(0)" ::: "memory")
#define WAIT_VM6()   asm volatile("s_waitcnt vmcnt(6)" ::: "memory")
#define WAIT_VM5()   asm volatile("s_waitcnt vmcnt(5)" ::: "memory")
#define WAIT_VM0()   asm volatile("s_waitcnt vmcnt(0)" ::: "memory")

// stage one A half-tile (H=0/1) of K-tile KT into buffer BUF
#define STAGE_A(BUF, H, KT) do {                                               \
    const long _k0 = (long)(KT) << 6;                                          \
    _Pragma("unroll")                                                          \
    for (int _i = 0; _i < AINSTR; ++_i) {                                      \
        const int _gi   = w + _i * 8;                                          \
        const int _s    = _gi / AHALF_GRP;                                     \
        const int _wg   = _gi % AHALF_GRP;                                     \
        const int _row0 = _s * (BM / 2) + (H) * (BM / 4) + _wg * 8;            \
        const int _grow = _row0 + (lane >> 3);                                 \
        async16(A + (m0 + _grow) * (long)K + _k0 +                             \
                    (((lane & 7) ^ (_grow & 7)) << 3),                         \
                smem + (BUF) * BUFU + _row0 * 64);                             \
    } } while (0)

// stage one B half-tile (H=0/1) of K-tile KT into buffer BUF
#define STAGE_B(BUF, H, KT) do {                                               \
    const long _k0 = (long)(KT) << 6;                                          \
    _Pragma("unroll")                                                          \
    for (int _i = 0; _i < 2; ++_i) {                                           \
        const int _gi   = w * 2 + _i;                                          \
        const int _row0 = (_gi >> 2) * 64 + (H) * 32 + (_gi & 3) * 8;          \
        const int _grow = _row0 + (lane >> 3);                                 \
        async16(Bt + (n0 + _grow) * (long)K + _k0 +                            \
                     (((lane & 7) ^ (_grow & 7)) << 3),                        \
                smem + (BUF) * BUFU + BM * 64 + _row0 * 64);                   \
    } } while (0)

// read A fragments for m-half MH into a[][] (swizzled ds_read_b128)
#define LOAD_A(BUF, MH) do {                                                   \
    _Pragma("unroll")                                                          \
    for (int _m = 0; _m < MF / 2; ++_m) {                                      \
        const int _row = wm * (BM / 2) + ((MH) * (MF / 2) + _m) * 16 + fr;     \
        _Pragma("unroll")                                                      \
        for (int _ks = 0; _ks < 2; ++_ks)                                      \
            a[_m][_ks] = *(const short8*)(smem + (BUF) * BUFU + _row * 64 +    \
                                          (((_ks * 4 + q) ^ (_row & 7)) << 3));\
    } } while (0)

// read B fragments for n-half NH into BREG[][]
#define LOAD_B(BUF, NH, BREG) do {                                             \
    _Pragma("unroll")                                                          \
    for (int _n = 0; _n < 2; ++_n) {                                           \
        const int _row = wn * 64 + ((NH) * 2 + _n) * 16 + fr;                  \
        _Pragma("unroll")                                                      \
        for (int _ks = 0; _ks < 2; ++_ks)                                      \
            BREG[_n][_ks] = *(const short8*)(smem + (BUF) * BUFU + BM * 64 +   \
                                             _row * 64 +                       \
                                          (((_ks * 4 + q) ^ (_row & 7)) << 3));\
    } } while (0)

// 16 (MF=8) / 8 (MF=4) MFMAs: quadrant (MH,NH) x K=64
#define MMA(MH, NH, BREG) do {                                                 \
    _Pragma("unroll")                                                          \
    for (int _m = 0; _m < MF / 2; ++_m)                                        \
    _Pragma("unroll")                                                          \
    for (int _n = 0; _n < 2; ++_n)                                             \
    _Pragma("unroll")                                                          \
    for (int _ks = 0; _ks < 2; ++_ks)                                          \
        acc[(MH) * (MF / 2) + _m][(NH) * 2 + _n] =                             \
            __builtin_amdgcn_mfma_f32_16x16x32_bf16(                           \
                a[_m][_ks], BREG[_n][_ks],                                     \
                acc[(MH) * (MF / 2) + _m][(NH) * 2 + _n], 0, 0, 0);            \
    } while (0)

template<int EPI, int MF>
__global__ __launch_bounds__(512, 2) void gemm8(
    const ushort* __restrict__ A, const ushort* __restrict__ Bt,
    int M, int N, int K,
    const void* __restrict__ bias, long bias_off,
    void* __restrict__ out, long ldo,
    float* __restrict__ hacc,
    const float* __restrict__ rowscale,
    const ushort* __restrict__ resid,
    const int* __restrict__ flag)
{
    constexpr int BM        = MF * 32;        // 128 or 256
    constexpr int AHALF_GRP = BM / 32;        // 8-row groups per section per A-half
    constexpr int AINSTR    = BM / 128;       // global_load_lds per wave per A-half
    constexpr int BUFU      = (BM + 256) * 64;// ushorts per double-buffer slot
    extern __shared__ ushort smem[];

    const int tid  = threadIdx.x;
    const int lane = tid & 63;
    const int w    = tid >> 6;
    const int wm   = w >> 2;                  // 0..1
    const int wn   = w & 3;                   // 0..3
    const int fr   = lane & 15;
    const int q    = lane >> 4;
    const long m0  = (long)blockIdx.y * BM;
    const long n0  = (long)blockIdx.x * 256;
    const int NT   = K >> 6;                  // K-tiles of 64 (K>=2048 here)

    floatx4 acc[MF][4] = {};
    short8 a[MF / 2][2];
    short8 b0[2][2], b1[2][2];

    // prologue: tile0 fully + 3 half-tiles of tile1 (order matches steady state)
    STAGE_A(0, 0, 0); STAGE_A(0, 1, 0); STAGE_B(0, 0, 0); STAGE_B(0, 1, 0);
    STAGE_A(1, 0, 1); STAGE_B(1, 0, 1); STAGE_B(1, 1, 1);
    if constexpr (MF == 8) WAIT_VM6(); else WAIT_VM5();   // tile0 resident
    BAR();

    for (int t = 0; t < NT; ++t) {
        const int cur = t & 1, nxt = cur ^ 1;
        // ---- P1: quadrant (0,0); stage A-half1 of tile t+1 -----------------
        LOAD_A(cur, 0);
        LOAD_B(cur, 0, b0);
        if (t + 1 < NT) STAGE_A(nxt, 1, t + 1);
        BAR(); WAIT_LGKM0();
        __builtin_amdgcn_s_setprio(1); MMA(0, 0, b0); __builtin_amdgcn_s_setprio(0);
        BAR();
        // ---- P2: quadrant (0,1); stage A-half0 of tile t+2 -----------------
        LOAD_B(cur, 1, b1);
        if (t + 2 < NT) STAGE_A(cur, 0, t + 2);
        BAR(); WAIT_LGKM0();
        __builtin_amdgcn_s_setprio(1); MMA(0, 1, b1); __builtin_amdgcn_s_setprio(0);
        BAR();
        // ---- P3: quadrant (1,1); stage B-half0 of tile t+2 -----------------
        LOAD_A(cur, 1);
        if (t + 2 < NT) STAGE_B(cur, 0, t + 2);
        BAR(); WAIT_LGKM0();
        __builtin_amdgcn_s_setprio(1); MMA(1, 1, b1); __builtin_amdgcn_s_setprio(0);
        BAR();
        // ---- P4: quadrant (1,0); stage B-half1 of tile t+2; counted vmcnt --
        if (t + 2 < NT) {
            STAGE_B(cur, 1, t + 2);
            if constexpr (MF == 8) WAIT_VM6(); else WAIT_VM5();
        } else {
            WAIT_VM0();                       // tail drain (last two tiles only)
        }
        BAR();
        __builtin_amdgcn_s_setprio(1); MMA(1, 0, b0); __builtin_amdgcn_s_setprio(0);
        BAR();
    }

    const int bf = *flag;
    // C[m][n]: m = i*16 + q*4 + r, n = j*16 + fr (m89-verified layout)
    #pragma unroll
    for (int i = 0; i < MF; ++i) {
        #pragma unroll
        for (int r = 0; r < 4; ++r) {
            const long m = m0 + wm * (BM / 2) + i * 16 + q * 4 + r;
            #pragma unroll
            for (int j = 0; j < 4; ++j) {
                const long n = n0 + wn * 64 + j * 16 + fr;
                float v = acc[i][j][r] + ldany(bias, bias_off + n, bf);
                if (EPI == EPI_SILU) {
                    v = v / (1.f + __expf(-v));
                    ((ushort*)out)[m * ldo + n] = f2b(v);
                } else if (EPI == EPI_BIAS) {
                    ((ushort*)out)[m * ldo + n] = f2b(v);
                } else if (EPI == EPI_EXPERT) {
                    hacc[m * (long)N + n] += rowscale[m * 4] * v;
                } else if (EPI == EPI_EXPSNAP) {
                    const long idx = m * (long)N + n;
                    const float nv = hacc[idx] + rowscale[m * 4] * v;
                    hacc[idx] = nv;
                    ((ushort*)out)[m * ldo + n] = f2b(nv);   // h4 snapshot
                } else if (EPI == EPI_CTX) {
                    hacc[m * (long)N + n] += v;
                } else {
                    v += b2f(resid[m * (long)N + n]);
                    if (bf) ((ushort*)out)[m * ldo + n] = f2b(v);
                    else    ((float*)out)[m * ldo + n]  = v;
                }
            }
        }
    }
}

// ---------------------------------------------------------------------------
// se gather: hA[m][2048 + j] = bf16(W_syn_emb[ids[m]][j]), j < 512
// ---------------------------------------------------------------------------
__global__ void gather_syn(const int* __restrict__ ids, const void* __restrict__ emb,
                           ushort* __restrict__ hA, const int* __restrict__ flag)
{
    const int bf = *flag;
    const long m = blockIdx.x;
    const int id = ids[m];
    const int j = threadIdx.x * 2;
    float a, b;
    if (bf) {
        ushort2 v = *(const ushort2*)((const ushort*)emb + (long)id * 512 + j);
        a = b2f(v.x); b = b2f(v.y);
    } else {
        float2 v = *(const float2*)((const float*)emb + (long)id * 512 + j);
        a = v.x; b = v.y;
    }
    ushort2 o; o.x = f2b(a); o.y = f2b(b);
    *(ushort2*)(hA + m * 2560 + 2048 + j) = o;
}

// ---------------------------------------------------------------------------
// gate + router; h3 = h2*gate in place (bf16) and into hacc (fp32)
// ---------------------------------------------------------------------------
__global__ __launch_bounds__(256) void gate_router(
    ushort* __restrict__ h2, float* __restrict__ hacc, float* __restrict__ probs,
    const void* __restrict__ Wg, const void* __restrict__ bg,
    const void* __restrict__ Wr, const void* __restrict__ br,
    const int* __restrict__ flag)
{
    const int bf = *flag;
    const long m = blockIdx.x;
    const int t = threadIdx.x;
    const int lane = t & 63;
    const int wv = t >> 6;
    ushort* row = h2 + m * 2048;

    float sg = 0.f, s0 = 0.f, s1 = 0.f, s2 = 0.f, s3 = 0.f;
    for (int k = t; k < 2048; k += 256) {
        const float h = b2f(row[k]);
        sg += h * ldany(Wg, k, bf);
        float r0v, r1v, r2v, r3v;
        if (bf) {
            ushort4 v = *(const ushort4*)((const ushort*)Wr + (long)k * 4);
            r0v = b2f(v.x); r1v = b2f(v.y); r2v = b2f(v.z); r3v = b2f(v.w);
        } else {
            float4 v = *(const float4*)((const float*)Wr + (long)k * 4);
            r0v = v.x; r1v = v.y; r2v = v.z; r3v = v.w;
        }
        s0 += h * r0v; s1 += h * r1v; s2 += h * r2v; s3 += h * r3v;
    }
    #pragma unroll
    for (int off = 32; off > 0; off >>= 1) {
        sg += __shfl_down(sg, off);
        s0 += __shfl_down(s0, off);
        s1 += __shfl_down(s1, off);
        s2 += __shfl_down(s2, off);
        s3 += __shfl_down(s3, off);
    }
    __shared__ float red[4][5];
    __shared__ float gate_bc;
    if (lane == 0) {
        red[wv][0] = sg; red[wv][1] = s0; red[wv][2] = s1;
        red[wv][3] = s2; red[wv][4] = s3;
    }
    __syncthreads();
    if (t == 0) {
        float G = red[0][0] + red[1][0] + red[2][0] + red[3][0];
        float R[4];
        #pragma unroll
        for (int e = 0; e < 4; e++)
            R[e] = red[0][1 + e] + red[1][1 + e] + red[2][1 + e] + red[3][1 + e];
        const float gate = 1.f / (1.f + __expf(-(G + ldany(bg, 0, bf))));
        float lg[4], mx = -1e30f;
        #pragma unroll
        for (int e = 0; e < 4; e++) {
            lg[e] = gate * R[e] + ldany(br, e, bf);
            mx = fmaxf(mx, lg[e]);
        }
        float p[4], s = 0.f;
        #pragma unroll
        for (int e = 0; e < 4; e++) { p[e] = __expf(lg[e] - mx); s += p[e]; }
        #pragma unroll
        for (int e = 0; e < 4; e++) probs[m * 4 + e] = p[e] / s;
        gate_bc = gate;
    }
    __syncthreads();
    const float gate = gate_bc;
    for (int k = t; k < 2048; k += 256) {
        const float v = b2f(row[k]) * gate;
        row[k] = f2b(v);
        hacc[m * 2048 + k] = v;
    }
}

// ---------------------------------------------------------------------------
// grouped conv1d (8 ch/group, k=3, pad 1) + combine: h5 = bf16(hacc + cb + pat)
// Block: 32 s-rows (+2 halo) x 512 channels, staged coalesced into LDS (bf16).
// Thread: 2 adjacent channels (same group), 48 weights in registers,
// 3x ds_read_b128 per s (16 unique addrs/wave -> 2-way alias = free).
// Grid: (S/32, D/512, B) = (64, 4, 2).
// ---------------------------------------------------------------------------
__global__ __launch_bounds__(256) void conv_combine(
    const ushort* __restrict__ h4, const float* __restrict__ hacc,
    const void* __restrict__ cw, const void* __restrict__ cb,
    ushort* __restrict__ h5, const int* __restrict__ flag)
{
    const int S = 2048, D = 2048;
    const int SC = 32;
    const int bf = *flag;
    const int b  = blockIdx.z;
    const int c0 = blockIdx.y * 512;
    const int s0 = blockIdx.x * SC;
    const int t  = threadIdx.x;

    __shared__ ushort tile[(SC + 2) * 512];   // 34 rows x 512 ch bf16 = 34 KB

    // per-thread channels c, c+1 (always in the same conv group)
    const int cp = 2 * t;                     // 0..510 within block
    const int c  = c0 + cp;
    float w0[3][8], w1[3][8];
    #pragma unroll
    for (int kk = 0; kk < 3; kk++)
        #pragma unroll
        for (int ii = 0; ii < 8; ii++) {
            w0[kk][ii] = ldany(cw, (long)c * 24 + ii * 3 + kk, bf);
            w1[kk][ii] = ldany(cw, (long)(c + 1) * 24 + ii * 3 + kk, bf);
        }
    const float bc0 = ldany(cb, c, bf);
    const float bc1 = ldany(cb, c + 1, bf);

    // coalesced staging: rows s0-1 .. s0+SC, 512 channels, 16B/lane contiguous
    for (int idx = t; idx < (SC + 2) * 64; idx += 256) {
        const int r  = idx >> 6;              // 0..33
        const int ch = (idx & 63) * 8;        // 0..504
        const int s  = s0 - 1 + r;
        short8 v = {};
        if (s >= 0 && s < S)
            v = *(const short8*)(h4 + ((long)b * S + s) * D + c0 + ch);
        *(short8*)(tile + r * 512 + ch) = v;
    }
    __syncthreads();

    const int gc8 = (cp >> 3) * 8;            // group's ushort offset in a row
    for (int sl = 0; sl < SC; ++sl) {
        float p0 = 0.f, p1 = 0.f;
        #pragma unroll
        for (int kk = 0; kk < 3; kk++) {
            short8 v = *(const short8*)(tile + (sl + kk) * 512 + gc8);
            #pragma unroll
            for (int ii = 0; ii < 8; ii++) {
                const float x = b2f((ushort)v[ii]);
                p0 += x * w0[kk][ii];
                p1 += x * w1[kk][ii];
            }
        }
        const long m = (long)b * S + s0 + sl;
        const float2 ha = *(const float2*)(hacc + m * D + c);
        ushort2 o; o.x = f2b(ha.x + bc0 + p0); o.y = f2b(ha.y + bc1 + p1);
        *(ushort2*)(h5 + m * D + c) = o;
    }
}

// ---------------------------------------------------------------------------
extern "C" void kernel_launch(void* const* d_in, const int* in_sizes, int n_in,
                              void* d_out, int out_size, void* d_ws, size_t ws_size,
                              hipStream_t stream)
{
    (void)in_sizes; (void)n_in; (void)out_size; (void)ws_size;
    const void* x        = d_in[0];
    const int*  syn      = (const int*)d_in[1];
    const void* W_in     = d_in[2];
    const void* b_in     = d_in[3];
    const void* W_synemb = d_in[4];
    const void* W_syn    = d_in[5];
    const void* b_syn    = d_in[6];
    const void* W_gate   = d_in[7];
    const void* b_gate   = d_in[8];
    const void* W_router = d_in[9];
    const void* b_router = d_in[10];
    const void* W_e1     = d_in[11];
    const void* b_e1     = d_in[12];
    const void* W_e2     = d_in[13];
    const void* b_e2     = d_in[14];
    const void* W_ctx    = d_in[15];
    const void* b_ctx    = d_in[16];
    const void* conv_w   = d_in[17];
    const void* conv_b   = d_in[18];
    const void* W_out    = d_in[19];
    const void* b_out    = d_in[20];

    char* ws = (char*)d_ws;
    int*    flag  = (int*)ws;                          // 256 B reserved
    ushort* WT    = (ushort*)(ws + 256);               // 16 MiB transposed weight
    ushort* xb    = (ushort*)(ws + 16777472);          // [4096][2048] bf16 x
    ushort* hA    = (ushort*)(ws + 33554688);          // [4096][2560] concat(h1,se); later h5 (ld 2048)
    ushort* eh    = (ushort*)(ws + 16777472);          // [4096][4096] overlaps xb+hA-head (expert phase only)
    ushort* h23   = (ushort*)(ws + 54526208);          // [4096][2048] h2 -> h3 -> h4(bf16)
    float*  probs = (float*)(ws + 71303424);           // [4096][4]
    float*  hacc  = (float*)(ws + 71368960);           // [4096][2048] fp32 accumulator
    const int M = 4096;
    dim3 blk(256);
    const int LDS4 = 98304;    // MF=4: 2*(128+256)*64*2 B
    const int LDS8 = 131072;   // MF=8: 2*(256+256)*64*2 B

    static bool attr_set = false;
    if (!attr_set) {
        (void)hipFuncSetAttribute(reinterpret_cast<const void*>(&gemm8<EPI_SILU,    4>),
                                  hipFuncAttributeMaxDynamicSharedMemorySize, LDS4);
        (void)hipFuncSetAttribute(reinterpret_cast<const void*>(&gemm8<EPI_BIAS,    4>),
                                  hipFuncAttributeMaxDynamicSharedMemorySize, LDS4);
        (void)hipFuncSetAttribute(reinterpret_cast<const void*>(&gemm8<EPI_EXPERT,  4>),
                                  hipFuncAttributeMaxDynamicSharedMemorySize, LDS4);
        (void)hipFuncSetAttribute(reinterpret_cast<const void*>(&gemm8<EPI_EXPSNAP, 4>),
                                  hipFuncAttributeMaxDynamicSharedMemorySize, LDS4);
        (void)hipFuncSetAttribute(reinterpret_cast<const void*>(&gemm8<EPI_CTX,     4>),
                                  hipFuncAttributeMaxDynamicSharedMemorySize, LDS4);
        (void)hipFuncSetAttribute(reinterpret_cast<const void*>(&gemm8<EPI_OUT,     4>),
                                  hipFuncAttributeMaxDynamicSharedMemorySize, LDS4);
        (void)hipFuncSetAttribute(reinterpret_cast<const void*>(&gemm8<EPI_SILU,    8>),
                                  hipFuncAttributeMaxDynamicSharedMemorySize, LDS8);
        attr_set = true;
    }

    // 0) dtype probe (re-runs every launch; ws is re-poisoned by harness)
    detect_dtype<<<dim3(1), dim3(64), 0, stream>>>((const unsigned*)W_in, flag);
    // 0b) xb = bf16(x)  [also the bf16 residual source for step 9]
    to_bf16_any<<<dim3(8192), blk, 0, stream>>>(x, xb, 2097152L, flag);

    // 1) h1 = silu(x @ W_in + b_in) -> hA[:, :2048] (ld 2560)
    transpose_any<<<dim3(32, 32), blk, 0, stream>>>(W_in, 0, WT, 2048, 2048, flag);
    gemm8<EPI_SILU, 4><<<dim3(8, 32), dim3(512), LDS4, stream>>>(
        xb, WT, M, 2048, 2048, b_in, 0, hA, 2560, nullptr, nullptr, nullptr, flag);
    // 2) se gather -> hA[:, 2048:2560]
    gather_syn<<<dim3(4096), blk, 0, stream>>>(syn, W_synemb, hA, flag);
    // 3) h2 = concat(h1,se) @ W_syn + b_syn -> h23
    transpose_any<<<dim3(32, 40), blk, 0, stream>>>(W_syn, 0, WT, 2560, 2048, flag);
    gemm8<EPI_BIAS, 4><<<dim3(8, 32), dim3(512), LDS4, stream>>>(
        hA, WT, M, 2048, 2560, b_syn, 0, h23, 2048, nullptr, nullptr, nullptr, flag);
    // 4) gate + router; h3 in place; hacc = h3
    gate_router<<<dim3(4096), blk, 0, stream>>>(
        h23, hacc, probs, W_gate, b_gate, W_router, b_router, flag);
    // 5) experts: hacc += probs_e * (silu(h3 @ We1 + b1) @ We2 + b2)
    //    e==3's e2-GEMM also emits the bf16 h4 snapshot into h23 (EPI_EXPSNAP);
    //    h23's h3 content is dead once e3's e1-GEMM has consumed it.
    for (int e = 0; e < 4; e++) {
        transpose_any<<<dim3(64, 32), blk, 0, stream>>>(
            W_e1, (long)e * 8388608, WT, 2048, 4096, flag);
        gemm8<EPI_SILU, 8><<<dim3(16, 16), dim3(512), LDS8, stream>>>(
            h23, WT, M, 4096, 2048, b_e1, (long)e * 4096, eh, 4096,
            nullptr, nullptr, nullptr, flag);
        transpose_any<<<dim3(32, 64), blk, 0, stream>>>(
            W_e2, (long)e * 8388608, WT, 4096, 2048, flag);
        if (e < 3)
            gemm8<EPI_EXPERT, 4><<<dim3(8, 32), dim3(512), LDS4, stream>>>(
                eh, WT, M, 2048, 4096, b_e2, (long)e * 2048, nullptr, 0,
                hacc, probs + e, nullptr, flag);
        else
            gemm8<EPI_EXPSNAP, 4><<<dim3(8, 32), dim3(512), LDS4, stream>>>(
                eh, WT, M, 2048, 4096, b_e2, (long)e * 2048, h23, 2048,
                hacc, probs + e, nullptr, flag);
    }
    // 5b) restore xb (eh clobbered it)
    to_bf16_any<<<dim3(8192), blk, 0, stream>>>(x, xb, 2097152L, flag);
    // 6) (fused into e3's EPI_EXPSNAP: h23 = bf16(hacc) = h4)
    // 7) hacc += h4 @ W_ctx + b_ctx
    transpose_any<<<dim3(32, 32), blk, 0, stream>>>(W_ctx, 0, WT, 2048, 2048, flag);
    gemm8<EPI_CTX, 4><<<dim3(8, 32), dim3(512), LDS4, stream>>>(
        h23, WT, M, 2048, 2048, b_ctx, 0, nullptr, 0, hacc, nullptr, nullptr, flag);
    // 8) h5 = bf16(hacc + conv_b + grouped_conv(h4)) -> hA (ld 2048)
    conv_combine<<<dim3(64, 4, 2), blk, 0, stream>>>(
        h23, hacc, conv_w, conv_b, hA, flag);
    // 9) out = h5 @ W_out + b_out + x
    transpose_any<<<dim3(32, 32), blk, 0, stream>>>(W_out, 0, WT, 2048, 2048, flag);
    gemm8<EPI_OUT, 4><<<dim3(8, 32), dim3(512), LDS4, stream>>>(
        hA, WT, M, 2048, 2048, b_out, 0, d_out, 2048, nullptr, nullptr, xb, flag);
}